// Round 1
// baseline (371.272 us; speedup 1.0000x reference)
//
#include <hip/hip_runtime.h>
#include <stdint.h>

typedef __attribute__((ext_vector_type(4))) float f32x4;
typedef __attribute__((ext_vector_type(8))) short bf16x8;
typedef __attribute__((ext_vector_type(4))) unsigned short u16x4;
typedef __attribute__((ext_vector_type(4))) unsigned int u32x4;

typedef __attribute__((address_space(3))) char lds_t;
typedef const __attribute__((address_space(1))) char gmem_t;

__device__ __forceinline__ float bf2f(unsigned short u) {
  union { unsigned int u; float f; } a; a.u = ((unsigned int)u) << 16; return a.f;
}
__device__ __forceinline__ unsigned short f2bf(float f) {
  union { float f; unsigned int u; } a; a.f = f;
  unsigned int r = a.u + 0x7fffu + ((a.u >> 16) & 1u);  // RNE (finite inputs)
  return (unsigned short)(r >> 16);
}

// ---------------- fp32 -> bf16 convert, 4 elems/thread ----------------
__global__ void cvt_kernel(const float* __restrict__ in, unsigned short* __restrict__ out, int n) {
  int i = (blockIdx.x * blockDim.x + threadIdx.x) * 4;
  if (i >= n) return;
  const f32x4 v = *(const f32x4*)(in + i);
  u16x4 o;
#pragma unroll
  for (int k = 0; k < 4; ++k) o[k] = f2bf(v[k]);
  *(u16x4*)(out + i) = o;
}

// ---------------- bf16 GEMM  C = A @ B^T  (A:[M][1024], B:[1024][1024]) ----------------
// 128x128 tile, BK=64, 4 waves (2x2), acc 4x4 of 16x16x32 MFMA.
// LDS staged via global_load_lds width=16 with XOR-chunk swizzle (both-sides, G21).
template<int OUT_BF16>
__global__ __launch_bounds__(256) void gemm_bt(
    const unsigned short* __restrict__ A,
    const unsigned short* __restrict__ B0, const unsigned short* __restrict__ B1,
    const unsigned short* __restrict__ B2,
    void* __restrict__ O0, void* __restrict__ O1, void* __restrict__ O2)
{
  constexpr int K = 1024, N = 1024;
  const int bz = blockIdx.z;
  const unsigned short* Bm = (bz == 0) ? B0 : (bz == 1 ? B1 : B2);
  void* Op = (bz == 0) ? O0 : (bz == 1 ? O1 : O2);
  const int bm0 = blockIdx.y * 128;
  const int bn0 = blockIdx.x * 128;
  const int t = threadIdx.x;
  const int l = t & 63;
  const int w = t >> 6;
  const int wr = w >> 1, wc = w & 1;

  __shared__ char smem[32768];
  char* sA = smem;
  char* sB = smem + 16384;

  f32x4 acc[4][4];
#pragma unroll
  for (int i = 0; i < 4; ++i)
#pragma unroll
    for (int j = 0; j < 4; ++j) acc[i][j] = f32x4{0.f, 0.f, 0.f, 0.f};

  // staging: each wave stages 8 rows x 128B per instruction; lane l -> row r0+(l>>3), lds chunk (l&7).
  // source chunk pre-swizzled so that LDS[r][c] = G[r][c ^ (r&7)].
  const int srow = l >> 3;
  const int schunk = (l & 7) ^ srow;
  const long long arowg = (long long)(bm0 + w * 32 + srow) * K;
  const long long browg = (long long)(bn0 + w * 32 + srow) * K;

  int aoff[4], boff[4];
#pragma unroll
  for (int i = 0; i < 4; ++i) {
    aoff[i] = (wr * 64 + i * 16 + (l & 15)) * 128;
    boff[i] = (wc * 64 + i * 16 + (l & 15)) * 128;
  }
  const int xr = l & 7;      // == (frag row) & 7
  const int chalf = l >> 4;  // 0..3

#define STAGE(kt_) do {                                                                     \
    const int kcol = (kt_) * 64 + schunk * 8;                                               \
    _Pragma("unroll")                                                                       \
    for (int i_ = 0; i_ < 4; ++i_) {                                                        \
      __builtin_amdgcn_global_load_lds((gmem_t*)(A + arowg + (long long)i_ * 8 * K + kcol), \
                                       (lds_t*)(sA + (w * 32 + i_ * 8) * 128), 16, 0, 0);   \
      __builtin_amdgcn_global_load_lds((gmem_t*)(Bm + browg + (long long)i_ * 8 * K + kcol),\
                                       (lds_t*)(sB + (w * 32 + i_ * 8) * 128), 16, 0, 0);   \
    }                                                                                       \
  } while (0)

  STAGE(0);
  __syncthreads();
  for (int kt = 0; kt < K / 64; ++kt) {
#pragma unroll
    for (int ks = 0; ks < 2; ++ks) {
      bf16x8 av[4], bv[4];
      const int choff = ((ks * 4 + chalf) ^ xr) * 16;
#pragma unroll
      for (int i = 0; i < 4; ++i) av[i] = *(const bf16x8*)(sA + aoff[i] + choff);
#pragma unroll
      for (int j = 0; j < 4; ++j) bv[j] = *(const bf16x8*)(sB + boff[j] + choff);
#pragma unroll
      for (int i = 0; i < 4; ++i)
#pragma unroll
        for (int j = 0; j < 4; ++j)
          acc[i][j] = __builtin_amdgcn_mfma_f32_16x16x32_bf16(av[i], bv[j], acc[i][j], 0, 0, 0);
    }
    __syncthreads();
    if (kt + 1 < K / 64) STAGE(kt + 1);
    __syncthreads();
  }
#undef STAGE

  // epilogue: C/D layout col = lane&15, row = (lane>>4)*4 + reg  [m89/m91]
  const int colb = bn0 + wc * 64 + (l & 15);
  const int rowb = bm0 + wr * 64 + (l >> 4) * 4;
#pragma unroll
  for (int i = 0; i < 4; ++i)
#pragma unroll
    for (int j = 0; j < 4; ++j)
#pragma unroll
      for (int r = 0; r < 4; ++r) {
        const long long idx = (long long)(rowb + i * 16 + r) * N + (colb + j * 16);
        if (OUT_BF16) ((unsigned short*)Op)[idx] = f2bf(acc[i][j][r]);
        else          ((float*)Op)[idx] = acc[i][j][r];
      }
}

// ---------------- l2norm(q), l2norm(k) per 64-chunk; v *= 1024^-sigmoid(nc[h]) ----------------
__global__ __launch_bounds__(256) void norm_scale(
    unsigned short* __restrict__ q, unsigned short* __restrict__ k,
    unsigned short* __restrict__ v, const float* __restrict__ nc)
{
  const int gid = blockIdx.x * 256 + threadIdx.x;
  const int wid = gid >> 6;          // chunk id: (row, head)
  const int lane = threadIdx.x & 63;
  const int row = wid >> 4;
  const int h = wid & 15;
  const long long base = (long long)row * 1024 + h * 64 + lane;

  float qv = bf2f(q[base]);
  float s = qv * qv;
#pragma unroll
  for (int m = 32; m; m >>= 1) s += __shfl_xor(s, m);
  q[base] = f2bf(qv / fmaxf(sqrtf(s), 1e-12f));

  float kv_ = bf2f(k[base]);
  float s2 = kv_ * kv_;
#pragma unroll
  for (int m = 32; m; m >>= 1) s2 += __shfl_xor(s2, m);
  k[base] = f2bf(kv_ / fmaxf(sqrtf(s2), 1e-12f));

  const float sig = 1.f / (1.f + expf(-nc[h]));
  const float vsc = expf(-6.9314718055994530942f * sig);  // 1024^-sig
  v[base] = f2bf(bf2f(v[base]) * vsc);
}

// ---------------- kv[d][e] = sum_c k[c][d]*v[c][e]  per (n,h), C split 4 ways ----------------
__global__ __launch_bounds__(256) void kv_kernel(
    const unsigned short* __restrict__ k, const unsigned short* __restrict__ v,
    float* __restrict__ kvout)
{
  const int h = blockIdx.x, n = blockIdx.y, part = blockIdx.z;
  const int t = threadIdx.x;
  __shared__ char sm[2 * 64 * 144];  // [64 rows][72 bf16] padded, k then v
  char* sk = sm;
  char* sv = sm + 64 * 144;
  const int d0 = (t & 15) * 4, e0 = (t >> 4) * 4;
  float acc[4][4] = {};
  const int sr = t >> 3, scc = t & 7;
  const long long gbase = ((long long)n * 1024) * 1024 + h * 64;
  for (int c0 = part * 256; c0 < part * 256 + 256; c0 += 64) {
#pragma unroll
    for (int p = 0; p < 2; ++p) {
      const int r = p * 32 + sr;
      u32x4 kd = *(const u32x4*)(k + gbase + (long long)(c0 + r) * 1024 + scc * 8);
      *(u32x4*)(sk + r * 144 + scc * 16) = kd;
      u32x4 vd = *(const u32x4*)(v + gbase + (long long)(c0 + r) * 1024 + scc * 8);
      *(u32x4*)(sv + r * 144 + scc * 16) = vd;
    }
    __syncthreads();
    for (int c = 0; c < 64; ++c) {
      const u16x4 ku = *(const u16x4*)(sk + c * 144 + d0 * 2);
      const u16x4 vu = *(const u16x4*)(sv + c * 144 + e0 * 2);
      float kf[4], vf[4];
#pragma unroll
      for (int i = 0; i < 4; ++i) { kf[i] = bf2f(ku[i]); vf[i] = bf2f(vu[i]); }
#pragma unroll
      for (int i = 0; i < 4; ++i)
#pragma unroll
        for (int j = 0; j < 4; ++j)
          acc[i][j] = fmaf(kf[i], vf[j], acc[i][j]);
    }
    __syncthreads();
  }
  float* o = kvout + ((long long)part * 256 + n * 16 + h) * 4096;
#pragma unroll
  for (int i = 0; i < 4; ++i)
#pragma unroll
    for (int j = 0; j < 4; ++j)
      o[(d0 + i) * 64 + e0 + j] = acc[i][j];
}

// ---------------- attn = q @ kv per (n,h); writes attn over q in place ----------------
__global__ __launch_bounds__(256) void attn_kernel(
    unsigned short* __restrict__ q, const float* __restrict__ kvf)
{
  const int cb = blockIdx.x, h = blockIdx.y, n = blockIdx.z;
  const int t = threadIdx.x;
  __shared__ float qs[64][65];
  __shared__ float kvs[64][68];
  const long long qrowbase = (((long long)n * 1024) + cb * 64) * 1024 + h * 64;
  {  // stage q chunk (64 rows x 64 bf16) as f32
    const int sr = t >> 3, scc = t & 7;
#pragma unroll
    for (int p = 0; p < 2; ++p) {
      const int r = p * 32 + sr;
      const u32x4 d = *(const u32x4*)(q + qrowbase + (long long)r * 1024 + scc * 8);
#pragma unroll
      for (int jj = 0; jj < 4; ++jj) {
        qs[r][scc * 8 + 2 * jj]     = bf2f((unsigned short)(d[jj] & 0xffffu));
        qs[r][scc * 8 + 2 * jj + 1] = bf2f((unsigned short)(d[jj] >> 16));
      }
    }
  }
  {  // stage kv = sum of 4 C-split parts
    const long long kvbase = ((long long)n * 16 + h) * 4096 + t * 16;
    const int dd = t >> 2, ee = (t & 3) * 16;
#pragma unroll
    for (int g = 0; g < 4; ++g) {
      f32x4 sum = f32x4{0.f, 0.f, 0.f, 0.f};
#pragma unroll
      for (int part = 0; part < 4; ++part)
        sum += *(const f32x4*)(kvf + (long long)part * 256 * 4096 + kvbase + g * 4);
      *(f32x4*)&kvs[dd][ee + g * 4] = sum;
    }
  }
  __syncthreads();
  const int r = t & 63, e0 = (t >> 6) * 16;
  float acc[16] = {};
  for (int d = 0; d < 64; ++d) {
    const float qv = qs[r][d];
#pragma unroll
    for (int g = 0; g < 4; ++g) {
      const f32x4 kvv = *(const f32x4*)&kvs[d][e0 + g * 4];
#pragma unroll
      for (int j = 0; j < 4; ++j) acc[g * 4 + j] = fmaf(qv, kvv[j], acc[g * 4 + j]);
    }
  }
  alignas(16) unsigned short u16[16];
#pragma unroll
  for (int j = 0; j < 16; ++j) u16[j] = f2bf(acc[j]);
  unsigned short* dst = q + qrowbase + (long long)r * 1024 + e0;
  *(u32x4*)dst = *(const u32x4*)&u16[0];
  *((u32x4*)dst + 1) = *(const u32x4*)&u16[8];
}

extern "C" void kernel_launch(void* const* d_in, const int* in_sizes, int n_in,
                              void* d_out, int out_size, void* d_ws, size_t ws_size,
                              hipStream_t stream) {
  (void)in_sizes; (void)n_in; (void)out_size; (void)ws_size;
  const float* x  = (const float*)d_in[0];
  const float* Wq = (const float*)d_in[1];
  const float* Wk = (const float*)d_in[2];
  const float* Wv = (const float*)d_in[3];
  const float* Wo = (const float*)d_in[4];
  const float* nc = (const float*)d_in[5];

  // d_out (64 MB fp32) doubles as scratch for xb (33.5 MB) + kvf (16 MB);
  // both are dead before the final GEMM overwrites d_out.
  unsigned short* xb = (unsigned short*)d_out;
  float* kvf = (float*)((char*)d_out + 16777216ll * 2);

  char* ws = (char*)d_ws;
  unsigned short* wqb = (unsigned short*)ws;
  unsigned short* wkb = wqb + 1048576;
  unsigned short* wvb = wkb + 1048576;
  unsigned short* wob = wvb + 1048576;
  unsigned short* qb  = wob + 1048576;   // also becomes attn output (in place)
  unsigned short* kb  = qb + 16777216;
  unsigned short* vb  = kb + 16777216;

  cvt_kernel<<<16384, 256, 0, stream>>>(x, xb, 16777216);
  cvt_kernel<<<1024, 256, 0, stream>>>(Wq, wqb, 1048576);
  cvt_kernel<<<1024, 256, 0, stream>>>(Wk, wkb, 1048576);
  cvt_kernel<<<1024, 256, 0, stream>>>(Wv, wvb, 1048576);
  cvt_kernel<<<1024, 256, 0, stream>>>(Wo, wob, 1048576);

  gemm_bt<1><<<dim3(8, 128, 3), 256, 0, stream>>>(xb, wqb, wkb, wvb, qb, kb, vb);
  norm_scale<<<65536, 256, 0, stream>>>(qb, kb, vb, nc);
  kv_kernel<<<dim3(16, 16, 4), 256, 0, stream>>>(kb, vb, kvf);
  attn_kernel<<<dim3(16, 16, 16), 256, 0, stream>>>(qb, kvf);
  gemm_bt<0><<<dim3(8, 128, 1), 256, 0, stream>>>(qb, wob, wob, wob, d_out, d_out, d_out);
}

// Round 2
// 302.839 us; speedup vs baseline: 1.2260x; 1.2260x over previous
//
#include <hip/hip_runtime.h>
#include <stdint.h>

typedef __attribute__((ext_vector_type(4))) float f32x4;
typedef __attribute__((ext_vector_type(8))) short bf16x8;
typedef __attribute__((ext_vector_type(4))) unsigned short u16x4;
typedef __attribute__((ext_vector_type(4))) unsigned int u32x4;

typedef __attribute__((address_space(3))) char lds_t;
typedef const __attribute__((address_space(1))) char gmem_t;

__device__ __forceinline__ float bf2f(unsigned short u) {
  union { unsigned int u; float f; } a; a.u = ((unsigned int)u) << 16; return a.f;
}
__device__ __forceinline__ unsigned short f2bf(float f) {
  union { float f; unsigned int u; } a; a.f = f;
  unsigned int r = a.u + 0x7fffu + ((a.u >> 16) & 1u);  // RNE (finite inputs)
  return (unsigned short)(r >> 16);
}

// ---------------- fp32 -> bf16 convert, 4 elems/thread ----------------
__global__ void cvt_kernel(const float* __restrict__ in, unsigned short* __restrict__ out, int n) {
  int i = (blockIdx.x * blockDim.x + threadIdx.x) * 4;
  if (i >= n) return;
  const f32x4 v = *(const f32x4*)(in + i);
  u16x4 o;
#pragma unroll
  for (int k = 0; k < 4; ++k) o[k] = f2bf(v[k]);
  *(u16x4*)(out + i) = o;
}

// ---------------- bf16 GEMM  C = A @ B^T ----------------
// A:[M][1024], B:[GX*128][1024]. 128x128 tile, BK=64, 4 waves (2x2),
// acc 4x4 of 16x16x32 MFMA. LDS via global_load_lds w=16, XOR-chunk swizzle (G21).
// Bijective XCD swizzle over the 1-D physical block id (T1).
// MODE 0: fp32 out to O0 (Wo GEMM). MODE 1: fused qkv epilogue:
//   sel = col/1024 -> q,k: per-(row,head) l2norm; v: *1024^-sigmoid(nc[h]); bf16 out.
template<int GX, int MODE>
__global__ __launch_bounds__(256) void gemm_bt(
    const unsigned short* __restrict__ A, const unsigned short* __restrict__ B,
    void* __restrict__ O0, void* __restrict__ O1, void* __restrict__ O2,
    const float* __restrict__ nc)
{
  constexpr int K = 1024;
  constexpr int NWG = GX * 128;
  constexpr int CPX = NWG >> 3;
  const int p = blockIdx.y * GX + blockIdx.x;          // physical dispatch order
  const int lid = (p & 7) * CPX + (p >> 3);            // XCD-contiguous logical id
  const int bm0 = (lid / GX) * 128;
  const int bn0 = (lid % GX) * 128;
  const int t = threadIdx.x;
  const int l = t & 63;
  const int w = t >> 6;
  const int wr = w >> 1, wc = w & 1;

  __shared__ char smem[32768];
  char* sA = smem;
  char* sB = smem + 16384;

  f32x4 acc[4][4];
#pragma unroll
  for (int i = 0; i < 4; ++i)
#pragma unroll
    for (int j = 0; j < 4; ++j) acc[i][j] = f32x4{0.f, 0.f, 0.f, 0.f};

  // staging: lane l -> row (l>>3), lds chunk (l&7); source chunk pre-swizzled
  // so LDS[r][c] = G[r][c ^ (r&7)]  (both-sides swizzle, G21).
  const int srow = l >> 3;
  const int schunk = (l & 7) ^ srow;
  const long long arowg = (long long)(bm0 + w * 32 + srow) * K;
  const long long browg = (long long)(bn0 + w * 32 + srow) * K;

  int aoff[4], boff[4];
#pragma unroll
  for (int i = 0; i < 4; ++i) {
    aoff[i] = (wr * 64 + i * 16 + (l & 15)) * 128;
    boff[i] = (wc * 64 + i * 16 + (l & 15)) * 128;
  }
  const int xr = l & 7;
  const int chalf = l >> 4;

#define STAGE(kt_) do {                                                                     \
    const int kcol = (kt_) * 64 + schunk * 8;                                               \
    _Pragma("unroll")                                                                       \
    for (int i_ = 0; i_ < 4; ++i_) {                                                        \
      __builtin_amdgcn_global_load_lds((gmem_t*)(A + arowg + (long long)i_ * 8 * K + kcol), \
                                       (lds_t*)(sA + (w * 32 + i_ * 8) * 128), 16, 0, 0);   \
      __builtin_amdgcn_global_load_lds((gmem_t*)(B + browg + (long long)i_ * 8 * K + kcol), \
                                       (lds_t*)(sB + (w * 32 + i_ * 8) * 128), 16, 0, 0);   \
    }                                                                                       \
  } while (0)

  STAGE(0);
  __syncthreads();
  for (int kt = 0; kt < K / 64; ++kt) {
#pragma unroll
    for (int ks = 0; ks < 2; ++ks) {
      bf16x8 av[4], bv[4];
      const int choff = ((ks * 4 + chalf) ^ xr) * 16;
#pragma unroll
      for (int i = 0; i < 4; ++i) av[i] = *(const bf16x8*)(sA + aoff[i] + choff);
#pragma unroll
      for (int j = 0; j < 4; ++j) bv[j] = *(const bf16x8*)(sB + boff[j] + choff);
#pragma unroll
      for (int i = 0; i < 4; ++i)
#pragma unroll
        for (int j = 0; j < 4; ++j)
          acc[i][j] = __builtin_amdgcn_mfma_f32_16x16x32_bf16(av[i], bv[j], acc[i][j], 0, 0, 0);
    }
    __syncthreads();
    if (kt + 1 < K / 64) STAGE(kt + 1);
    __syncthreads();
  }
#undef STAGE

  // C/D layout: col = lane&15, row = (lane>>4)*4 + reg  [m89/m91]
  const int wcol0 = bn0 + wc * 64;      // wave's 64-col span == one head (MODE 1)
  const int rowb = bm0 + wr * 64 + (l >> 4) * 4;

  if (MODE == 0) {
    float* Op = (float*)O0;
    const int colb = wcol0 + (l & 15);
#pragma unroll
    for (int i = 0; i < 4; ++i)
#pragma unroll
      for (int j = 0; j < 4; ++j)
#pragma unroll
        for (int r = 0; r < 4; ++r)
          Op[(long long)(rowb + i * 16 + r) * 1024 + (colb + j * 16)] = acc[i][j][r];
  } else {
    const int sel = wcol0 >> 10;                       // 0:q 1:k 2:v
    unsigned short* Op = (unsigned short*)(sel == 0 ? O0 : sel == 1 ? O1 : O2);
    const int col_in = wcol0 & 1023;
    if (sel < 2) {
      // per-row l2norm over this head's 64 cols: sum_j acc^2, 16-lane reduce
#pragma unroll
      for (int i = 0; i < 4; ++i)
#pragma unroll
        for (int r = 0; r < 4; ++r) {
          float s = 0.f;
#pragma unroll
          for (int j = 0; j < 4; ++j) s += acc[i][j][r] * acc[i][j][r];
          s += __shfl_xor(s, 1); s += __shfl_xor(s, 2);
          s += __shfl_xor(s, 4); s += __shfl_xor(s, 8);
          const float inv = 1.f / fmaxf(sqrtf(s), 1e-12f);
#pragma unroll
          for (int j = 0; j < 4; ++j) acc[i][j][r] *= inv;
        }
    } else {
      const int h = col_in >> 6;
      const float sig = 1.f / (1.f + expf(-nc[h]));
      const float vsc = expf(-6.9314718055994530942f * sig);  // 1024^-sig
#pragma unroll
      for (int i = 0; i < 4; ++i)
#pragma unroll
        for (int j = 0; j < 4; ++j)
#pragma unroll
          for (int r = 0; r < 4; ++r) acc[i][j][r] *= vsc;
    }
    const int colb = col_in + (l & 15);
#pragma unroll
    for (int i = 0; i < 4; ++i)
#pragma unroll
      for (int j = 0; j < 4; ++j)
#pragma unroll
        for (int r = 0; r < 4; ++r)
          Op[(long long)(rowb + i * 16 + r) * 1024 + (colb + j * 16)] = f2bf(acc[i][j][r]);
  }
}

// ---------------- kv[d][e] = sum_c k[c][d]*v[c][e]  per (n,h), C split 4 ways ----------------
__global__ __launch_bounds__(256) void kv_kernel(
    const unsigned short* __restrict__ k, const unsigned short* __restrict__ v,
    float* __restrict__ kvout)
{
  const int h = blockIdx.x, n = blockIdx.y, part = blockIdx.z;
  const int t = threadIdx.x;
  __shared__ char sm[2 * 64 * 144];  // [64 rows][72 bf16] padded, k then v
  char* sk = sm;
  char* sv = sm + 64 * 144;
  const int d0 = (t & 15) * 4, e0 = (t >> 4) * 4;
  float acc[4][4] = {};
  const int sr = t >> 3, scc = t & 7;
  const long long gbase = ((long long)n * 1024) * 1024 + h * 64;
  for (int c0 = part * 256; c0 < part * 256 + 256; c0 += 64) {
#pragma unroll
    for (int p = 0; p < 2; ++p) {
      const int r = p * 32 + sr;
      u32x4 kd = *(const u32x4*)(k + gbase + (long long)(c0 + r) * 1024 + scc * 8);
      *(u32x4*)(sk + r * 144 + scc * 16) = kd;
      u32x4 vd = *(const u32x4*)(v + gbase + (long long)(c0 + r) * 1024 + scc * 8);
      *(u32x4*)(sv + r * 144 + scc * 16) = vd;
    }
    __syncthreads();
    for (int c = 0; c < 64; ++c) {
      const u16x4 ku = *(const u16x4*)(sk + c * 144 + d0 * 2);
      const u16x4 vu = *(const u16x4*)(sv + c * 144 + e0 * 2);
      float kf[4], vf[4];
#pragma unroll
      for (int i = 0; i < 4; ++i) { kf[i] = bf2f(ku[i]); vf[i] = bf2f(vu[i]); }
#pragma unroll
      for (int i = 0; i < 4; ++i)
#pragma unroll
        for (int j = 0; j < 4; ++j)
          acc[i][j] = fmaf(kf[i], vf[j], acc[i][j]);
    }
    __syncthreads();
  }
  float* o = kvout + ((long long)part * 256 + n * 16 + h) * 4096;
#pragma unroll
  for (int i = 0; i < 4; ++i)
#pragma unroll
    for (int j = 0; j < 4; ++j)
      o[(d0 + i) * 64 + e0 + j] = acc[i][j];
}

// ---------------- attn = q @ kv per (n,h); writes attn over q in place ----------------
__global__ __launch_bounds__(256) void attn_kernel(
    unsigned short* __restrict__ q, const float* __restrict__ kvf)
{
  const int cb = blockIdx.x, h = blockIdx.y, n = blockIdx.z;
  const int t = threadIdx.x;
  __shared__ float qs[64][65];
  __shared__ float kvs[64][68];
  const long long qrowbase = (((long long)n * 1024) + cb * 64) * 1024 + h * 64;
  {  // stage q chunk (64 rows x 64 bf16) as f32
    const int sr = t >> 3, scc = t & 7;
#pragma unroll
    for (int p = 0; p < 2; ++p) {
      const int r = p * 32 + sr;
      const u32x4 d = *(const u32x4*)(q + qrowbase + (long long)r * 1024 + scc * 8);
#pragma unroll
      for (int jj = 0; jj < 4; ++jj) {
        qs[r][scc * 8 + 2 * jj]     = bf2f((unsigned short)(d[jj] & 0xffffu));
        qs[r][scc * 8 + 2 * jj + 1] = bf2f((unsigned short)(d[jj] >> 16));
      }
    }
  }
  {  // stage kv = sum of 4 C-split parts
    const long long kvbase = ((long long)n * 16 + h) * 4096 + t * 16;
    const int dd = t >> 2, ee = (t & 3) * 16;
#pragma unroll
    for (int g = 0; g < 4; ++g) {
      f32x4 sum = f32x4{0.f, 0.f, 0.f, 0.f};
#pragma unroll
      for (int part = 0; part < 4; ++part)
        sum += *(const f32x4*)(kvf + (long long)part * 256 * 4096 + kvbase + g * 4);
      *(f32x4*)&kvs[dd][ee + g * 4] = sum;
    }
  }
  __syncthreads();
  const int r = t & 63, e0 = (t >> 6) * 16;
  float acc[16] = {};
  for (int d = 0; d < 64; ++d) {
    const float qv = qs[r][d];
#pragma unroll
    for (int g = 0; g < 4; ++g) {
      const f32x4 kvv = *(const f32x4*)&kvs[d][e0 + g * 4];
#pragma unroll
      for (int j = 0; j < 4; ++j) acc[g * 4 + j] = fmaf(qv, kvv[j], acc[g * 4 + j]);
    }
  }
  alignas(16) unsigned short u16[16];
#pragma unroll
  for (int j = 0; j < 16; ++j) u16[j] = f2bf(acc[j]);
  unsigned short* dst = q + qrowbase + (long long)r * 1024 + e0;
  *(u32x4*)dst = *(const u32x4*)&u16[0];
  *((u32x4*)dst + 1) = *(const u32x4*)&u16[8];
}

extern "C" void kernel_launch(void* const* d_in, const int* in_sizes, int n_in,
                              void* d_out, int out_size, void* d_ws, size_t ws_size,
                              hipStream_t stream) {
  (void)in_sizes; (void)n_in; (void)out_size; (void)ws_size;
  const float* x  = (const float*)d_in[0];
  const float* Wq = (const float*)d_in[1];
  const float* Wk = (const float*)d_in[2];
  const float* Wv = (const float*)d_in[3];
  const float* Wo = (const float*)d_in[4];
  const float* nc = (const float*)d_in[5];

  // d_out (64 MB fp32) doubles as scratch for xb (32 MB) + kvf (16 MB);
  // both are dead before the final GEMM overwrites d_out.
  unsigned short* xb = (unsigned short*)d_out;
  float* kvf = (float*)((char*)d_out + 16777216ll * 2);

  char* ws = (char*)d_ws;
  unsigned short* wqkv = (unsigned short*)ws;          // [3072][1024] = Wq;Wk;Wv
  unsigned short* wob  = wqkv + 3 * 1048576;
  unsigned short* qb   = wob + 1048576;                // becomes attn output in place
  unsigned short* kb   = qb + 16777216;
  unsigned short* vb   = kb + 16777216;

  cvt_kernel<<<16384, 256, 0, stream>>>(x, xb, 16777216);
  cvt_kernel<<<1024, 256, 0, stream>>>(Wq, wqkv, 1048576);
  cvt_kernel<<<1024, 256, 0, stream>>>(Wk, wqkv + 1048576, 1048576);
  cvt_kernel<<<1024, 256, 0, stream>>>(Wv, wqkv + 2097152, 1048576);
  cvt_kernel<<<1024, 256, 0, stream>>>(Wo, wob, 1048576);

  // QKV: one fused N=3072 GEMM, norm/scale fused in epilogue
  gemm_bt<24, 1><<<dim3(24, 128), 256, 0, stream>>>(xb, wqkv, qb, kb, vb, nc);
  kv_kernel<<<dim3(16, 16, 4), 256, 0, stream>>>(kb, vb, kvf);
  attn_kernel<<<dim3(16, 16, 16), 256, 0, stream>>>(qb, kvf);
  // out = attn @ Wo^T (fp32 out)
  gemm_bt<8, 0><<<dim3(8, 128), 256, 0, stream>>>(qb, wob, d_out, nullptr, nullptr, nullptr);
}

// Round 3
// 287.716 us; speedup vs baseline: 1.2904x; 1.0526x over previous
//
#include <hip/hip_runtime.h>
#include <stdint.h>

typedef __attribute__((ext_vector_type(4))) float f32x4;
typedef __attribute__((ext_vector_type(8))) short bf16x8;
typedef __attribute__((ext_vector_type(4))) unsigned short u16x4;
typedef __attribute__((ext_vector_type(4))) unsigned int u32x4;

typedef __attribute__((address_space(3))) char lds_t;
typedef const __attribute__((address_space(1))) char gmem_t;

__device__ __forceinline__ float bf2f(unsigned short u) {
  union { unsigned int u; float f; } a; a.u = ((unsigned int)u) << 16; return a.f;
}
__device__ __forceinline__ unsigned short f2bf(float f) {
  union { float f; unsigned int u; } a; a.f = f;
  unsigned int r = a.u + 0x7fffu + ((a.u >> 16) & 1u);  // RNE (finite inputs)
  return (unsigned short)(r >> 16);
}

// ---------------- fp32 -> bf16 convert, 4 elems/thread ----------------
__global__ void cvt_kernel(const float* __restrict__ in, unsigned short* __restrict__ out, int n) {
  int i = (blockIdx.x * blockDim.x + threadIdx.x) * 4;
  if (i >= n) return;
  const f32x4 v = *(const f32x4*)(in + i);
  u16x4 o;
#pragma unroll
  for (int k = 0; k < 4; ++k) o[k] = f2bf(v[k]);
  *(u16x4*)(out + i) = o;
}

// ---------------- bf16 GEMM  C = A @ B^T, phase-pipelined counted-vmcnt ----------------
// A:[M][1024], B:[GX*128][1024]. BM=256,BN=128,BK=64; 8 waves (4M x 2N), per-wave 64x64 out.
// 3 LDS buffers (48KB each), prefetch 2 K-tiles ahead, vmcnt(6) per K-tile (T3+T4),
// setprio around MFMA (T5), 16B-chunk XOR swizzle both-sides (T2/G21), XCD swizzle (T1).
// MODE 0: fp32 out to O0. MODE 1: fused qkv epilogue (l2norm q,k / sigmoid-scale v; bf16).
template<int GX, int MODE>
__global__ __launch_bounds__(512, 2) void gemm8p(
    const unsigned short* __restrict__ A, const unsigned short* __restrict__ B,
    void* __restrict__ O0, void* __restrict__ O1, void* __restrict__ O2,
    const float* __restrict__ nc)
{
  constexpr int K = 1024;
  constexpr int NT = K / 64;                 // 16 K-tiles
  constexpr int BUF = 49152;                 // 32KB A + 16KB B
  constexpr int NWG = GX * 64;
  constexpr int CPX = NWG >> 3;
  const int p = blockIdx.y * GX + blockIdx.x;
  const int lid = (p & 7) * CPX + (p >> 3);  // XCD-contiguous (NWG % 8 == 0)
  const int bm0 = (lid / GX) * 256;
  const int bn0 = (lid % GX) * 128;
  const int t = threadIdx.x;
  const int l = t & 63;
  const int w = t >> 6;
  const int wm = w >> 1;                     // 0..3 -> rows wm*64
  const int wn = w & 1;                      // 0..1 -> cols wn*64

  __shared__ char smem[3 * BUF];

  // ---- staging addressing (per thread): row-in-round = t>>3 (0..63), chunk = t&7 ----
  const int srow = t >> 3;
  const int schunk = t & 7;
  const int sck = schunk ^ (srow & 7);       // pre-swizzled source chunk (G21)

#define STAGE_A(dst_, kt_, r_)                                                                  \
  __builtin_amdgcn_global_load_lds(                                                            \
      (gmem_t*)(A + (long long)(bm0 + (r_) * 64 + srow) * K + (kt_) * 64 + sck * 8),           \
      (lds_t*)((dst_) + ((r_) * 64 + srow) * 128 + schunk * 16), 16, 0, 0)
#define STAGE_B(dst_, kt_, r_)                                                                  \
  __builtin_amdgcn_global_load_lds(                                                            \
      (gmem_t*)(B + (long long)(bn0 + (r_) * 64 + srow) * K + (kt_) * 64 + sck * 8),           \
      (lds_t*)((dst_) + 32768 + ((r_) * 64 + srow) * 128 + schunk * 16), 16, 0, 0)

  // ---- ds_read addressing ----
  const int xr = l & 7;
  const int chalf = l >> 4;                  // 0..3
  int aoff[4], boff[4];
#pragma unroll
  for (int i = 0; i < 4; ++i) aoff[i] = (wm * 64 + i * 16 + (l & 15)) * 128;
#pragma unroll
  for (int j = 0; j < 4; ++j) boff[j] = 32768 + (wn * 64 + j * 16 + (l & 15)) * 128;

  f32x4 acc[4][4];
#pragma unroll
  for (int i = 0; i < 4; ++i)
#pragma unroll
    for (int j = 0; j < 4; ++j) acc[i][j] = f32x4{0.f, 0.f, 0.f, 0.f};

  // ---- prologue: stage tiles 0 and 1 (6 loads each) ----
  {
    char* b0 = smem;
    STAGE_A(b0, 0, 0); STAGE_A(b0, 0, 1); STAGE_A(b0, 0, 2); STAGE_A(b0, 0, 3);
    STAGE_B(b0, 0, 0); STAGE_B(b0, 0, 1);
    char* b1 = smem + BUF;
    STAGE_A(b1, 1, 0); STAGE_A(b1, 1, 1); STAGE_A(b1, 1, 2); STAGE_A(b1, 1, 3);
    STAGE_B(b1, 1, 0); STAGE_B(b1, 1, 1);
  }
  asm volatile("s_waitcnt vmcnt(6)" ::: "memory");   // tile 0 landed
  __builtin_amdgcn_s_barrier();
  __builtin_amdgcn_sched_barrier(0);

  for (int kt = 0; kt < NT; ++kt) {
    char* bc = smem + (kt % 3) * BUF;
    char* bs = smem + ((kt + 2) % 3) * BUF;
    const bool st = (kt + 2) < NT;
    const int ks2 = kt + 2;
    bf16x8 bv[4][2];

    // ======== phase 0: B frags + A frags i=0,1 ; stage A rounds 0-2 ========
    if (st) { STAGE_A(bs, ks2, 0); STAGE_A(bs, ks2, 1); STAGE_A(bs, ks2, 2); }
    {
      bf16x8 av[2][2];
#pragma unroll
      for (int j = 0; j < 4; ++j)
#pragma unroll
        for (int ks = 0; ks < 2; ++ks)
          bv[j][ks] = *(const bf16x8*)(bc + boff[j] + (((ks * 4 + chalf) ^ xr) * 16));
#pragma unroll
      for (int il = 0; il < 2; ++il)
#pragma unroll
        for (int ks = 0; ks < 2; ++ks)
          av[il][ks] = *(const bf16x8*)(bc + aoff[il] + (((ks * 4 + chalf) ^ xr) * 16));
      __builtin_amdgcn_s_barrier();
      __builtin_amdgcn_sched_barrier(0);
      asm volatile("s_waitcnt lgkmcnt(0)" ::: "memory");
      __builtin_amdgcn_sched_barrier(0);
      __builtin_amdgcn_s_setprio(1);
#pragma unroll
      for (int il = 0; il < 2; ++il)
#pragma unroll
        for (int j = 0; j < 4; ++j)
#pragma unroll
          for (int ks = 0; ks < 2; ++ks)
            acc[il][j] = __builtin_amdgcn_mfma_f32_16x16x32_bf16(av[il][ks], bv[j][ks], acc[il][j], 0, 0, 0);
      __builtin_amdgcn_s_setprio(0);
      __builtin_amdgcn_s_barrier();
      __builtin_amdgcn_sched_barrier(0);
    }
    // ======== phase 1: A frags i=2,3 (B reused) ; stage A round 3 + B rounds 0,1 ========
    if (st) { STAGE_A(bs, ks2, 3); STAGE_B(bs, ks2, 0); STAGE_B(bs, ks2, 1); }
    {
      bf16x8 av[2][2];
#pragma unroll
      for (int il = 0; il < 2; ++il)
#pragma unroll
        for (int ks = 0; ks < 2; ++ks)
          av[il][ks] = *(const bf16x8*)(bc + aoff[2 + il] + (((ks * 4 + chalf) ^ xr) * 16));
      __builtin_amdgcn_s_barrier();
      __builtin_amdgcn_sched_barrier(0);
      asm volatile("s_waitcnt lgkmcnt(0)" ::: "memory");
      __builtin_amdgcn_sched_barrier(0);
      __builtin_amdgcn_s_setprio(1);
#pragma unroll
      for (int il = 0; il < 2; ++il)
#pragma unroll
        for (int j = 0; j < 4; ++j)
#pragma unroll
          for (int ks = 0; ks < 2; ++ks)
            acc[2 + il][j] = __builtin_amdgcn_mfma_f32_16x16x32_bf16(av[il][ks], bv[j][ks], acc[2 + il][j], 0, 0, 0);
      __builtin_amdgcn_s_setprio(0);
      // counted vmcnt: tile t+1 landed, tile t+2's 6 loads stay in flight (T4)
      if (kt < NT - 2) { asm volatile("s_waitcnt vmcnt(6)" ::: "memory"); }
      else             { asm volatile("s_waitcnt vmcnt(0)" ::: "memory"); }
      __builtin_amdgcn_s_barrier();
      __builtin_amdgcn_sched_barrier(0);
    }
  }
#undef STAGE_A
#undef STAGE_B

  // ---- epilogue: C/D layout col = lane&15, row = (lane>>4)*4 + reg ----
  const int wcol0 = bn0 + wn * 64;           // 64-col span == one head (MODE 1)
  const int rowb = bm0 + wm * 64 + (l >> 4) * 4;

  if (MODE == 0) {
    float* Op = (float*)O0;
    const int colb = wcol0 + (l & 15);
#pragma unroll
    for (int i = 0; i < 4; ++i)
#pragma unroll
      for (int j = 0; j < 4; ++j)
#pragma unroll
        for (int r = 0; r < 4; ++r)
          Op[(long long)(rowb + i * 16 + r) * 1024 + (colb + j * 16)] = acc[i][j][r];
  } else {
    const int sel = wcol0 >> 10;             // 0:q 1:k 2:v
    unsigned short* Op = (unsigned short*)(sel == 0 ? O0 : sel == 1 ? O1 : O2);
    const int col_in = wcol0 & 1023;
    if (sel < 2) {
#pragma unroll
      for (int i = 0; i < 4; ++i)
#pragma unroll
        for (int r = 0; r < 4; ++r) {
          float s = 0.f;
#pragma unroll
          for (int j = 0; j < 4; ++j) s += acc[i][j][r] * acc[i][j][r];
          s += __shfl_xor(s, 1); s += __shfl_xor(s, 2);
          s += __shfl_xor(s, 4); s += __shfl_xor(s, 8);
          const float inv = 1.f / fmaxf(sqrtf(s), 1e-12f);
#pragma unroll
          for (int j = 0; j < 4; ++j) acc[i][j][r] *= inv;
        }
    } else {
      const int h = col_in >> 6;
      const float sig = 1.f / (1.f + expf(-nc[h]));
      const float vsc = expf(-6.9314718055994530942f * sig);  // 1024^-sig
#pragma unroll
      for (int i = 0; i < 4; ++i)
#pragma unroll
        for (int j = 0; j < 4; ++j)
#pragma unroll
          for (int r = 0; r < 4; ++r) acc[i][j][r] *= vsc;
    }
    const int colb = col_in + (l & 15);
#pragma unroll
    for (int i = 0; i < 4; ++i)
#pragma unroll
      for (int j = 0; j < 4; ++j)
#pragma unroll
        for (int r = 0; r < 4; ++r)
          Op[(long long)(rowb + i * 16 + r) * 1024 + (colb + j * 16)] = f2bf(acc[i][j][r]);
  }
}

// ---------------- kv[d][e] = sum_c k[c][d]*v[c][e]  per (n,h), C split 4 ways ----------------
__global__ __launch_bounds__(256) void kv_kernel(
    const unsigned short* __restrict__ k, const unsigned short* __restrict__ v,
    float* __restrict__ kvout)
{
  const int h = blockIdx.x, n = blockIdx.y, part = blockIdx.z;
  const int t = threadIdx.x;
  __shared__ char sm[2 * 64 * 144];  // [64 rows][72 bf16] padded, k then v
  char* sk = sm;
  char* sv = sm + 64 * 144;
  const int d0 = (t & 15) * 4, e0 = (t >> 4) * 4;
  float acc[4][4] = {};
  const int sr = t >> 3, scc = t & 7;
  const long long gbase = ((long long)n * 1024) * 1024 + h * 64;
  for (int c0 = part * 256; c0 < part * 256 + 256; c0 += 64) {
#pragma unroll
    for (int p = 0; p < 2; ++p) {
      const int r = p * 32 + sr;
      u32x4 kd = *(const u32x4*)(k + gbase + (long long)(c0 + r) * 1024 + scc * 8);
      *(u32x4*)(sk + r * 144 + scc * 16) = kd;
      u32x4 vd = *(const u32x4*)(v + gbase + (long long)(c0 + r) * 1024 + scc * 8);
      *(u32x4*)(sv + r * 144 + scc * 16) = vd;
    }
    __syncthreads();
    for (int c = 0; c < 64; ++c) {
      const u16x4 ku = *(const u16x4*)(sk + c * 144 + d0 * 2);
      const u16x4 vu = *(const u16x4*)(sv + c * 144 + e0 * 2);
      float kf[4], vf[4];
#pragma unroll
      for (int i = 0; i < 4; ++i) { kf[i] = bf2f(ku[i]); vf[i] = bf2f(vu[i]); }
#pragma unroll
      for (int i = 0; i < 4; ++i)
#pragma unroll
        for (int j = 0; j < 4; ++j)
          acc[i][j] = fmaf(kf[i], vf[j], acc[i][j]);
    }
    __syncthreads();
  }
  float* o = kvout + ((long long)part * 256 + n * 16 + h) * 4096;
#pragma unroll
  for (int i = 0; i < 4; ++i)
#pragma unroll
    for (int j = 0; j < 4; ++j)
      o[(d0 + i) * 64 + e0 + j] = acc[i][j];
}

// ---------------- attn = q @ kv per (n,h); writes attn over q in place ----------------
__global__ __launch_bounds__(256) void attn_kernel(
    unsigned short* __restrict__ q, const float* __restrict__ kvf)
{
  const int cb = blockIdx.x, h = blockIdx.y, n = blockIdx.z;
  const int t = threadIdx.x;
  __shared__ float qs[64][65];
  __shared__ float kvs[64][68];
  const long long qrowbase = (((long long)n * 1024) + cb * 64) * 1024 + h * 64;
  {  // stage q chunk (64 rows x 64 bf16) as f32
    const int sr = t >> 3, scc = t & 7;
#pragma unroll
    for (int p = 0; p < 2; ++p) {
      const int r = p * 32 + sr;
      const u32x4 d = *(const u32x4*)(q + qrowbase + (long long)r * 1024 + scc * 8);
#pragma unroll
      for (int jj = 0; jj < 4; ++jj) {
        qs[r][scc * 8 + 2 * jj]     = bf2f((unsigned short)(d[jj] & 0xffffu));
        qs[r][scc * 8 + 2 * jj + 1] = bf2f((unsigned short)(d[jj] >> 16));
      }
    }
  }
  {  // stage kv = sum of 4 C-split parts
    const long long kvbase = ((long long)n * 16 + h) * 4096 + t * 16;
    const int dd = t >> 2, ee = (t & 3) * 16;
#pragma unroll
    for (int g = 0; g < 4; ++g) {
      f32x4 sum = f32x4{0.f, 0.f, 0.f, 0.f};
#pragma unroll
      for (int part = 0; part < 4; ++part)
        sum += *(const f32x4*)(kvf + (long long)part * 256 * 4096 + kvbase + g * 4);
      *(f32x4*)&kvs[dd][ee + g * 4] = sum;
    }
  }
  __syncthreads();
  const int r = t & 63, e0 = (t >> 6) * 16;
  float acc[16] = {};
  for (int d = 0; d < 64; ++d) {
    const float qv = qs[r][d];
#pragma unroll
    for (int g = 0; g < 4; ++g) {
      const f32x4 kvv = *(const f32x4*)&kvs[d][e0 + g * 4];
#pragma unroll
      for (int j = 0; j < 4; ++j) acc[g * 4 + j] = fmaf(qv, kvv[j], acc[g * 4 + j]);
    }
  }
  alignas(16) unsigned short u16[16];
#pragma unroll
  for (int j = 0; j < 16; ++j) u16[j] = f2bf(acc[j]);
  unsigned short* dst = q + qrowbase + (long long)r * 1024 + e0;
  *(u32x4*)dst = *(const u32x4*)&u16[0];
  *((u32x4*)dst + 1) = *(const u32x4*)&u16[8];
}

extern "C" void kernel_launch(void* const* d_in, const int* in_sizes, int n_in,
                              void* d_out, int out_size, void* d_ws, size_t ws_size,
                              hipStream_t stream) {
  (void)in_sizes; (void)n_in; (void)out_size; (void)ws_size;
  const float* x  = (const float*)d_in[0];
  const float* Wq = (const float*)d_in[1];
  const float* Wk = (const float*)d_in[2];
  const float* Wv = (const float*)d_in[3];
  const float* Wo = (const float*)d_in[4];
  const float* nc = (const float*)d_in[5];

  // d_out (64 MB fp32) doubles as scratch for xb (32 MB) + kvf (16 MB);
  // both are dead before the final GEMM overwrites d_out.
  unsigned short* xb = (unsigned short*)d_out;
  float* kvf = (float*)((char*)d_out + 16777216ll * 2);

  char* ws = (char*)d_ws;
  unsigned short* wqkv = (unsigned short*)ws;          // [3072][1024] = Wq;Wk;Wv
  unsigned short* wob  = wqkv + 3 * 1048576;
  unsigned short* qb   = wob + 1048576;                // becomes attn output in place
  unsigned short* kb   = qb + 16777216;
  unsigned short* vb   = kb + 16777216;

  cvt_kernel<<<16384, 256, 0, stream>>>(x, xb, 16777216);
  cvt_kernel<<<1024, 256, 0, stream>>>(Wq, wqkv, 1048576);
  cvt_kernel<<<1024, 256, 0, stream>>>(Wk, wqkv + 1048576, 1048576);
  cvt_kernel<<<1024, 256, 0, stream>>>(Wv, wqkv + 2097152, 1048576);
  cvt_kernel<<<1024, 256, 0, stream>>>(Wo, wob, 1048576);

  // QKV: one fused N=3072 GEMM (BM=256,BN=128), norm/scale fused in epilogue
  gemm8p<24, 1><<<dim3(24, 64), 512, 0, stream>>>(xb, wqkv, qb, kb, vb, nc);
  kv_kernel<<<dim3(16, 16, 4), 256, 0, stream>>>(kb, vb, kvf);
  attn_kernel<<<dim3(16, 16, 16), 256, 0, stream>>>(qb, kvf);
  // out = attn @ Wo^T (fp32 out)
  gemm8p<8, 0><<<dim3(8, 64), 512, 0, stream>>>(qb, wob, d_out, nullptr, nullptr, nullptr);
}

// Round 4
// 265.675 us; speedup vs baseline: 1.3975x; 1.0830x over previous
//
#include <hip/hip_runtime.h>
#include <stdint.h>

typedef __attribute__((ext_vector_type(4))) float f32x4;
typedef __attribute__((ext_vector_type(8))) short bf16x8;
typedef __attribute__((ext_vector_type(4))) unsigned short u16x4;
typedef __attribute__((ext_vector_type(4))) unsigned int u32x4;

typedef __attribute__((address_space(3))) char lds_t;
typedef const __attribute__((address_space(1))) char gmem_t;

__device__ __forceinline__ float bf2f(unsigned short u) {
  union { unsigned int u; float f; } a; a.u = ((unsigned int)u) << 16; return a.f;
}
__device__ __forceinline__ unsigned short f2bf(float f) {
  union { float f; unsigned int u; } a; a.f = f;
  unsigned int r = a.u + 0x7fffu + ((a.u >> 16) & 1u);  // RNE (finite inputs)
  return (unsigned short)(r >> 16);
}

// ---------------- fp32 -> bf16 convert, 4 elems/thread ----------------
__global__ void cvt_kernel(const float* __restrict__ in, unsigned short* __restrict__ out, int n) {
  int i = (blockIdx.x * blockDim.x + threadIdx.x) * 4;
  if (i >= n) return;
  const f32x4 v = *(const f32x4*)(in + i);
  u16x4 o;
#pragma unroll
  for (int k = 0; k < 4; ++k) o[k] = f2bf(v[k]);
  *(u16x4*)(out + i) = o;
}

// ---------------- bf16 GEMM  C = A @ B^T — faithful 256^2 8-phase template (m201/m204) ----
// BM=BN=256, BK=64, 16 K-tiles. 8 waves = 2M x 4N, per-wave 128x64 out (acc[8][4]).
// LDS 128KB = 2 slots x (A 32KB + B 32KB); staging unit = half-tile (16KB = 2 loads).
// Per K-tile: 4 phases x {ds_read subtile; stage 1 half; barrier; lgkm(0); 16 MFMA; barrier},
// B frags read at phase 0 and held in regs. vmcnt(4) once per tile (never 0 mid-loop).
// Ledger: A(u+1) staged ph0-1 of tile u (overwrites A(u-1), last read ph3(u-1));
//         B(u+2) staged ph2-3 of tile u (overwrites B(u), last read ph0(u)).
// MODE 0: fp32 out. MODE 1: fused qkv epilogue (l2norm q,k / sigmoid-scale v; bf16 out).
template<int GX, int MODE>
__global__ __launch_bounds__(512, 2) void gemm256(
    const unsigned short* __restrict__ A, const unsigned short* __restrict__ B,
    void* __restrict__ O0, void* __restrict__ O1, void* __restrict__ O2,
    const float* __restrict__ nc)
{
  constexpr int K = 1024;
  constexpr int NT = K / 64;
  constexpr int NWG = GX * 64;
  constexpr int CPX = NWG >> 3;
  const int p = blockIdx.y * GX + blockIdx.x;
  const int lid = (p & 7) * CPX + (p >> 3);        // bijective (NWG % 8 == 0)
  const int bm0 = (lid / GX) * 256;
  const int bn0 = (lid % GX) * 256;
  const int t = threadIdx.x;
  const int l = t & 63;
  const int w = t >> 6;
  const int wm = w >> 2;                           // 0..1 -> rows wm*128
  const int wn = w & 3;                            // 0..3 -> cols wn*64

  __shared__ char smem[131072];

  // staging: lane row = t>>3 (0..63), chunk = t&7; source chunk pre-swizzled (G21)
  const int srow = t >> 3;
  const int schunk = t & 7;
  const int sck = schunk ^ (srow & 7);

#define STAGE_A(so_, kt_, lam_)                                                                  \
  __builtin_amdgcn_global_load_lds(                                                             \
      (gmem_t*)(A + (long long)(bm0 + (lam_) * 64 + srow) * K + (kt_) * 64 + sck * 8),          \
      (lds_t*)(smem + (so_) + ((lam_) * 64 + srow) * 128 + schunk * 16), 16, 0, 0)
#define STAGE_B(so_, kt_, lam_)                                                                  \
  __builtin_amdgcn_global_load_lds(                                                             \
      (gmem_t*)(B + (long long)(bn0 + (lam_) * 64 + srow) * K + (kt_) * 64 + sck * 8),          \
      (lds_t*)(smem + (so_) + 32768 + ((lam_) * 64 + srow) * 128 + schunk * 16), 16, 0, 0)

  // ds_read addressing
  const int xr = l & 7;
  const int chalf = l >> 4;                        // 0..3
  int aoff[8], boff[4];
#pragma unroll
  for (int fr = 0; fr < 8; ++fr) aoff[fr] = (wm * 128 + fr * 16 + (l & 15)) * 128;
#pragma unroll
  for (int fc = 0; fc < 4; ++fc) boff[fc] = 32768 + (wn * 64 + fc * 16 + (l & 15)) * 128;

  f32x4 acc[8][4];
#pragma unroll
  for (int i = 0; i < 8; ++i)
#pragma unroll
    for (int j = 0; j < 4; ++j) acc[i][j] = f32x4{0.f, 0.f, 0.f, 0.f};

  // ---- prologue: tile0 A+B -> slot0; tile1 B -> slot1 (12 loads) ----
#pragma unroll
  for (int lam = 0; lam < 4; ++lam) STAGE_A(0, 0, lam);
#pragma unroll
  for (int lam = 0; lam < 4; ++lam) STAGE_B(0, 0, lam);
#pragma unroll
  for (int lam = 0; lam < 4; ++lam) STAGE_B(65536, 1, lam);
  asm volatile("s_waitcnt vmcnt(4)" ::: "memory");  // tile0's 8 loads landed
  __builtin_amdgcn_s_barrier();
  __builtin_amdgcn_sched_barrier(0);

  for (int u = 0; u < NT; ++u) {
    const int slot = (u & 1) << 16;
    const int nslot = slot ^ 65536;
    bf16x8 bv[4][2];
#pragma unroll
    for (int q = 0; q < 4; ++q) {
      // ---- ds-load register subtile ----
      if (q == 0) {
#pragma unroll
        for (int j = 0; j < 4; ++j)
#pragma unroll
          for (int ks = 0; ks < 2; ++ks)
            bv[j][ks] = *(const bf16x8*)(smem + slot + boff[j] + (((ks * 4 + chalf) ^ xr) * 16));
      }
      bf16x8 av[2][2];
#pragma unroll
      for (int d = 0; d < 2; ++d)
#pragma unroll
        for (int ks = 0; ks < 2; ++ks)
          av[d][ks] = *(const bf16x8*)(smem + slot + aoff[2 * q + d] + (((ks * 4 + chalf) ^ xr) * 16));
      // ---- stage 1 half-tile ----
      if (q == 0)      { if (u + 1 < NT) { STAGE_A(nslot, u + 1, 0); STAGE_A(nslot, u + 1, 1); } }
      else if (q == 1) { if (u + 1 < NT) { STAGE_A(nslot, u + 1, 2); STAGE_A(nslot, u + 1, 3); } }
      else if (q == 2) { if (u + 2 < NT) { STAGE_B(slot, u + 2, 0);  STAGE_B(slot, u + 2, 1); } }
      else             { if (u + 2 < NT) { STAGE_B(slot, u + 2, 2);  STAGE_B(slot, u + 2, 3); } }
      __builtin_amdgcn_s_barrier();
      asm volatile("s_waitcnt lgkmcnt(0)" ::: "memory");
      __builtin_amdgcn_sched_barrier(0);
      __builtin_amdgcn_s_setprio(1);
#pragma unroll
      for (int d = 0; d < 2; ++d)
#pragma unroll
        for (int j = 0; j < 4; ++j)
#pragma unroll
          for (int ks = 0; ks < 2; ++ks)
            acc[2 * q + d][j] =
                __builtin_amdgcn_mfma_f32_16x16x32_bf16(av[d][ks], bv[j][ks], acc[2 * q + d][j], 0, 0, 0);
      __builtin_amdgcn_s_setprio(0);
      if (q == 3) {
        if (u + 2 < NT) { asm volatile("s_waitcnt vmcnt(4)" ::: "memory"); }
        else            { asm volatile("s_waitcnt vmcnt(0)" ::: "memory"); }
      }
      __builtin_amdgcn_s_barrier();
      __builtin_amdgcn_sched_barrier(0);
    }
  }
#undef STAGE_A
#undef STAGE_B

  // ---- epilogue: C/D layout col = lane&15, row = (lane>>4)*4 + reg ----
  const int wcol0 = bn0 + wn * 64;                 // 64-col span == one head (MODE 1)
  const int rowb = bm0 + wm * 128 + (l >> 4) * 4;

  if (MODE == 0) {
    float* Op = (float*)O0;
    const int colb = wcol0 + (l & 15);
#pragma unroll
    for (int i = 0; i < 8; ++i)
#pragma unroll
      for (int j = 0; j < 4; ++j)
#pragma unroll
        for (int r = 0; r < 4; ++r)
          Op[(long long)(rowb + i * 16 + r) * 1024 + (colb + j * 16)] = acc[i][j][r];
  } else {
    const int sel = wcol0 >> 10;                   // 0:q 1:k 2:v
    unsigned short* Op = (unsigned short*)(sel == 0 ? O0 : sel == 1 ? O1 : O2);
    const int col_in = wcol0 & 1023;
    if (sel < 2) {
#pragma unroll
      for (int i = 0; i < 8; ++i)
#pragma unroll
        for (int r = 0; r < 4; ++r) {
          float s = 0.f;
#pragma unroll
          for (int j = 0; j < 4; ++j) s += acc[i][j][r] * acc[i][j][r];
          s += __shfl_xor(s, 1); s += __shfl_xor(s, 2);
          s += __shfl_xor(s, 4); s += __shfl_xor(s, 8);
          const float inv = 1.f / fmaxf(sqrtf(s), 1e-12f);
#pragma unroll
          for (int j = 0; j < 4; ++j) acc[i][j][r] *= inv;
        }
    } else {
      const int h = col_in >> 6;
      const float sig = 1.f / (1.f + expf(-nc[h]));
      const float vsc = expf(-6.9314718055994530942f * sig);  // 1024^-sig
#pragma unroll
      for (int i = 0; i < 8; ++i)
#pragma unroll
        for (int j = 0; j < 4; ++j)
#pragma unroll
          for (int r = 0; r < 4; ++r) acc[i][j][r] *= vsc;
    }
    const int colb = col_in + (l & 15);
#pragma unroll
    for (int i = 0; i < 8; ++i)
#pragma unroll
      for (int j = 0; j < 4; ++j)
#pragma unroll
        for (int r = 0; r < 4; ++r)
          Op[(long long)(rowb + i * 16 + r) * 1024 + (colb + j * 16)] = f2bf(acc[i][j][r]);
  }
}

// ---------------- kv[d][e] = sum_c k[c][d]*v[c][e]  per (n,h), C split 4 ways ----------------
__global__ __launch_bounds__(256) void kv_kernel(
    const unsigned short* __restrict__ k, const unsigned short* __restrict__ v,
    float* __restrict__ kvout)
{
  const int h = blockIdx.x, n = blockIdx.y, part = blockIdx.z;
  const int t = threadIdx.x;
  __shared__ char sm[2 * 64 * 144];  // [64 rows][72 bf16] padded, k then v
  char* sk = sm;
  char* sv = sm + 64 * 144;
  const int d0 = (t & 15) * 4, e0 = (t >> 4) * 4;
  float acc[4][4] = {};
  const int sr = t >> 3, scc = t & 7;
  const long long gbase = ((long long)n * 1024) * 1024 + h * 64;
  for (int c0 = part * 256; c0 < part * 256 + 256; c0 += 64) {
#pragma unroll
    for (int p = 0; p < 2; ++p) {
      const int r = p * 32 + sr;
      u32x4 kd = *(const u32x4*)(k + gbase + (long long)(c0 + r) * 1024 + scc * 8);
      *(u32x4*)(sk + r * 144 + scc * 16) = kd;
      u32x4 vd = *(const u32x4*)(v + gbase + (long long)(c0 + r) * 1024 + scc * 8);
      *(u32x4*)(sv + r * 144 + scc * 16) = vd;
    }
    __syncthreads();
    for (int c = 0; c < 64; ++c) {
      const u16x4 ku = *(const u16x4*)(sk + c * 144 + d0 * 2);
      const u16x4 vu = *(const u16x4*)(sv + c * 144 + e0 * 2);
      float kf[4], vf[4];
#pragma unroll
      for (int i = 0; i < 4; ++i) { kf[i] = bf2f(ku[i]); vf[i] = bf2f(vu[i]); }
#pragma unroll
      for (int i = 0; i < 4; ++i)
#pragma unroll
        for (int j = 0; j < 4; ++j)
          acc[i][j] = fmaf(kf[i], vf[j], acc[i][j]);
    }
    __syncthreads();
  }
  float* o = kvout + ((long long)part * 256 + n * 16 + h) * 4096;
#pragma unroll
  for (int i = 0; i < 4; ++i)
#pragma unroll
    for (int j = 0; j < 4; ++j)
      o[(d0 + i) * 64 + e0 + j] = acc[i][j];
}

// ---------------- attn = q @ kv per (n,h); writes attn over q in place ----------------
__global__ __launch_bounds__(256) void attn_kernel(
    unsigned short* __restrict__ q, const float* __restrict__ kvf)
{
  const int cb = blockIdx.x, h = blockIdx.y, n = blockIdx.z;
  const int t = threadIdx.x;
  __shared__ float qs[64][65];
  __shared__ float kvs[64][68];
  const long long qrowbase = (((long long)n * 1024) + cb * 64) * 1024 + h * 64;
  {  // stage q chunk (64 rows x 64 bf16) as f32
    const int sr = t >> 3, scc = t & 7;
#pragma unroll
    for (int p = 0; p < 2; ++p) {
      const int r = p * 32 + sr;
      const u32x4 d = *(const u32x4*)(q + qrowbase + (long long)r * 1024 + scc * 8);
#pragma unroll
      for (int jj = 0; jj < 4; ++jj) {
        qs[r][scc * 8 + 2 * jj]     = bf2f((unsigned short)(d[jj] & 0xffffu));
        qs[r][scc * 8 + 2 * jj + 1] = bf2f((unsigned short)(d[jj] >> 16));
      }
    }
  }
  {  // stage kv = sum of 4 C-split parts
    const long long kvbase = ((long long)n * 16 + h) * 4096 + t * 16;
    const int dd = t >> 2, ee = (t & 3) * 16;
#pragma unroll
    for (int g = 0; g < 4; ++g) {
      f32x4 sum = f32x4{0.f, 0.f, 0.f, 0.f};
#pragma unroll
      for (int part = 0; part < 4; ++part)
        sum += *(const f32x4*)(kvf + (long long)part * 256 * 4096 + kvbase + g * 4);
      *(f32x4*)&kvs[dd][ee + g * 4] = sum;
    }
  }
  __syncthreads();
  const int r = t & 63, e0 = (t >> 6) * 16;
  float acc[16] = {};
  for (int d = 0; d < 64; ++d) {
    const float qv = qs[r][d];
#pragma unroll
    for (int g = 0; g < 4; ++g) {
      const f32x4 kvv = *(const f32x4*)&kvs[d][e0 + g * 4];
#pragma unroll
      for (int j = 0; j < 4; ++j) acc[g * 4 + j] = fmaf(qv, kvv[j], acc[g * 4 + j]);
    }
  }
  alignas(16) unsigned short u16[16];
#pragma unroll
  for (int j = 0; j < 16; ++j) u16[j] = f2bf(acc[j]);
  unsigned short* dst = q + qrowbase + (long long)r * 1024 + e0;
  *(u32x4*)dst = *(const u32x4*)&u16[0];
  *((u32x4*)dst + 1) = *(const u32x4*)&u16[8];
}

extern "C" void kernel_launch(void* const* d_in, const int* in_sizes, int n_in,
                              void* d_out, int out_size, void* d_ws, size_t ws_size,
                              hipStream_t stream) {
  (void)in_sizes; (void)n_in; (void)out_size; (void)ws_size;
  const float* x  = (const float*)d_in[0];
  const float* Wq = (const float*)d_in[1];
  const float* Wk = (const float*)d_in[2];
  const float* Wv = (const float*)d_in[3];
  const float* Wo = (const float*)d_in[4];
  const float* nc = (const float*)d_in[5];

  // d_out (64 MB fp32) doubles as scratch for xb (32 MB) + kvf (16 MB);
  // both are dead before the final GEMM overwrites d_out.
  unsigned short* xb = (unsigned short*)d_out;
  float* kvf = (float*)((char*)d_out + 16777216ll * 2);

  char* ws = (char*)d_ws;
  unsigned short* wqkv = (unsigned short*)ws;          // [3072][1024] = Wq;Wk;Wv
  unsigned short* wob  = wqkv + 3 * 1048576;
  unsigned short* qb   = wob + 1048576;                // becomes attn output in place
  unsigned short* kb   = qb + 16777216;
  unsigned short* vb   = kb + 16777216;

  cvt_kernel<<<16384, 256, 0, stream>>>(x, xb, 16777216);
  cvt_kernel<<<1024, 256, 0, stream>>>(Wq, wqkv, 1048576);
  cvt_kernel<<<1024, 256, 0, stream>>>(Wk, wqkv + 1048576, 1048576);
  cvt_kernel<<<1024, 256, 0, stream>>>(Wv, wqkv + 2097152, 1048576);
  cvt_kernel<<<1024, 256, 0, stream>>>(Wo, wob, 1048576);

  // QKV: one fused N=3072 GEMM (256^2 tiles), norm/scale fused in epilogue
  gemm256<12, 1><<<dim3(12, 64), 512, 0, stream>>>(xb, wqkv, qb, kb, vb, nc);
  kv_kernel<<<dim3(16, 16, 4), 256, 0, stream>>>(kb, vb, kvf);
  attn_kernel<<<dim3(16, 16, 16), 256, 0, stream>>>(qb, kvf);
  // out = attn @ Wo^T (fp32 out)
  gemm256<4, 0><<<dim3(4, 64), 512, 0, stream>>>(qb, wob, d_out, nullptr, nullptr, nullptr);
}

// Round 5
// 209.381 us; speedup vs baseline: 1.7732x; 1.2689x over previous
//
#include <hip/hip_runtime.h>
#include <stdint.h>

typedef __attribute__((ext_vector_type(4))) float f32x4;
typedef __attribute__((ext_vector_type(8))) short bf16x8;
typedef __attribute__((ext_vector_type(4))) unsigned short u16x4;
typedef __attribute__((ext_vector_type(4))) unsigned int u32x4;

typedef __attribute__((address_space(3))) char lds_t;
typedef const __attribute__((address_space(1))) char gmem_t;

__device__ __forceinline__ float bf2f(unsigned short u) {
  union { unsigned int u; float f; } a; a.u = ((unsigned int)u) << 16; return a.f;
}
__device__ __forceinline__ unsigned short f2bf(float f) {
  union { float f; unsigned int u; } a; a.f = f;
  unsigned int r = a.u + 0x7fffu + ((a.u >> 16) & 1u);  // RNE (finite inputs)
  return (unsigned short)(r >> 16);
}

// ---------------- fp32 -> bf16 convert, 8 elems/thread ----------------
__global__ void cvt_kernel(const float* __restrict__ in, unsigned short* __restrict__ out, int n) {
  int i = (blockIdx.x * blockDim.x + threadIdx.x) * 8;
  if (i >= n) return;
  const f32x4 a = *(const f32x4*)(in + i);
  const f32x4 b = *(const f32x4*)(in + i + 4);
  alignas(16) unsigned short o[8];
#pragma unroll
  for (int k = 0; k < 4; ++k) { o[k] = f2bf(a[k]); o[4 + k] = f2bf(b[k]); }
  *(u32x4*)(out + i) = *(const u32x4*)o;
}

// all four weights in one launch (blockIdx.y selects)
__global__ void cvtw_kernel(const float* __restrict__ W0, const float* __restrict__ W1,
                            const float* __restrict__ W2, const float* __restrict__ W3,
                            unsigned short* __restrict__ wqkv, unsigned short* __restrict__ wob) {
  const int s = blockIdx.y;
  const float* in = (s == 0) ? W0 : (s == 1) ? W1 : (s == 2) ? W2 : W3;
  unsigned short* out = (s < 3) ? (wqkv + s * 1048576) : wob;
  int i = (blockIdx.x * blockDim.x + threadIdx.x) * 8;
  const f32x4 a = *(const f32x4*)(in + i);
  const f32x4 b = *(const f32x4*)(in + i + 4);
  alignas(16) unsigned short o[8];
#pragma unroll
  for (int k = 0; k < 4; ++k) { o[k] = f2bf(a[k]); o[4 + k] = f2bf(b[k]); }
  *(u32x4*)(out + i) = *(const u32x4*)o;
}

// ---------------- bf16 GEMM  C = A @ B^T — 256^2 8-phase template (m201/m204) ----------------
// MODE 0: fp32 out. MODE 1: fused qkv epilogue — q: l2norm, normal layout;
// k,v: l2norm / sigmoid-scale, written TRANSPOSED per (n,h) as [64][1024] (c-fastest).
template<int GX, int MODE>
__global__ __launch_bounds__(512, 2) void gemm256(
    const unsigned short* __restrict__ A, const unsigned short* __restrict__ B,
    void* __restrict__ O0, void* __restrict__ O1, void* __restrict__ O2,
    const float* __restrict__ nc)
{
  constexpr int K = 1024;
  constexpr int NT = K / 64;
  constexpr int NWG = GX * 64;
  constexpr int CPX = NWG >> 3;
  const int p = blockIdx.y * GX + blockIdx.x;
  const int lid = (p & 7) * CPX + (p >> 3);        // bijective (NWG % 8 == 0)
  const int bm0 = (lid / GX) * 256;
  const int bn0 = (lid % GX) * 256;
  const int t = threadIdx.x;
  const int l = t & 63;
  const int w = t >> 6;
  const int wm = w >> 2;
  const int wn = w & 3;

  __shared__ char smem[131072];

  const int srow = t >> 3;
  const int schunk = t & 7;
  const int sck = schunk ^ (srow & 7);

#define STAGE_A(so_, kt_, lam_)                                                                  \
  __builtin_amdgcn_global_load_lds(                                                             \
      (gmem_t*)(A + (long long)(bm0 + (lam_) * 64 + srow) * K + (kt_) * 64 + sck * 8),          \
      (lds_t*)(smem + (so_) + ((lam_) * 64 + srow) * 128 + schunk * 16), 16, 0, 0)
#define STAGE_B(so_, kt_, lam_)                                                                  \
  __builtin_amdgcn_global_load_lds(                                                             \
      (gmem_t*)(B + (long long)(bn0 + (lam_) * 64 + srow) * K + (kt_) * 64 + sck * 8),          \
      (lds_t*)(smem + (so_) + 32768 + ((lam_) * 64 + srow) * 128 + schunk * 16), 16, 0, 0)

  const int xr = l & 7;
  const int chalf = l >> 4;
  int aoff[8], boff[4];
#pragma unroll
  for (int fr = 0; fr < 8; ++fr) aoff[fr] = (wm * 128 + fr * 16 + (l & 15)) * 128;
#pragma unroll
  for (int fc = 0; fc < 4; ++fc) boff[fc] = 32768 + (wn * 64 + fc * 16 + (l & 15)) * 128;

  f32x4 acc[8][4];
#pragma unroll
  for (int i = 0; i < 8; ++i)
#pragma unroll
    for (int j = 0; j < 4; ++j) acc[i][j] = f32x4{0.f, 0.f, 0.f, 0.f};

#pragma unroll
  for (int lam = 0; lam < 4; ++lam) STAGE_A(0, 0, lam);
#pragma unroll
  for (int lam = 0; lam < 4; ++lam) STAGE_B(0, 0, lam);
#pragma unroll
  for (int lam = 0; lam < 4; ++lam) STAGE_B(65536, 1, lam);
  asm volatile("s_waitcnt vmcnt(4)" ::: "memory");
  __builtin_amdgcn_s_barrier();
  __builtin_amdgcn_sched_barrier(0);

  for (int u = 0; u < NT; ++u) {
    const int slot = (u & 1) << 16;
    const int nslot = slot ^ 65536;
    bf16x8 bv[4][2];
#pragma unroll
    for (int q = 0; q < 4; ++q) {
      if (q == 0) {
#pragma unroll
        for (int j = 0; j < 4; ++j)
#pragma unroll
          for (int ks = 0; ks < 2; ++ks)
            bv[j][ks] = *(const bf16x8*)(smem + slot + boff[j] + (((ks * 4 + chalf) ^ xr) * 16));
      }
      bf16x8 av[2][2];
#pragma unroll
      for (int d = 0; d < 2; ++d)
#pragma unroll
        for (int ks = 0; ks < 2; ++ks)
          av[d][ks] = *(const bf16x8*)(smem + slot + aoff[2 * q + d] + (((ks * 4 + chalf) ^ xr) * 16));
      if (q == 0)      { if (u + 1 < NT) { STAGE_A(nslot, u + 1, 0); STAGE_A(nslot, u + 1, 1); } }
      else if (q == 1) { if (u + 1 < NT) { STAGE_A(nslot, u + 1, 2); STAGE_A(nslot, u + 1, 3); } }
      else if (q == 2) { if (u + 2 < NT) { STAGE_B(slot, u + 2, 0);  STAGE_B(slot, u + 2, 1); } }
      else             { if (u + 2 < NT) { STAGE_B(slot, u + 2, 2);  STAGE_B(slot, u + 2, 3); } }
      __builtin_amdgcn_s_barrier();
      asm volatile("s_waitcnt lgkmcnt(0)" ::: "memory");
      __builtin_amdgcn_sched_barrier(0);
      __builtin_amdgcn_s_setprio(1);
#pragma unroll
      for (int d = 0; d < 2; ++d)
#pragma unroll
        for (int j = 0; j < 4; ++j)
#pragma unroll
          for (int ks = 0; ks < 2; ++ks)
            acc[2 * q + d][j] =
                __builtin_amdgcn_mfma_f32_16x16x32_bf16(av[d][ks], bv[j][ks], acc[2 * q + d][j], 0, 0, 0);
      __builtin_amdgcn_s_setprio(0);
      if (q == 3) {
        if (u + 2 < NT) { asm volatile("s_waitcnt vmcnt(4)" ::: "memory"); }
        else            { asm volatile("s_waitcnt vmcnt(0)" ::: "memory"); }
      }
      __builtin_amdgcn_s_barrier();
      __builtin_amdgcn_sched_barrier(0);
    }
  }
#undef STAGE_A
#undef STAGE_B

  const int wcol0 = bn0 + wn * 64;
  const int rowb = bm0 + wm * 128 + (l >> 4) * 4;

  if (MODE == 0) {
    float* Op = (float*)O0;
    const int colb = wcol0 + (l & 15);
#pragma unroll
    for (int i = 0; i < 8; ++i)
#pragma unroll
      for (int j = 0; j < 4; ++j)
#pragma unroll
        for (int r = 0; r < 4; ++r)
          Op[(long long)(rowb + i * 16 + r) * 1024 + (colb + j * 16)] = acc[i][j][r];
  } else {
    const int sel = wcol0 >> 10;                   // 0:q 1:k 2:v
    const int col_in = wcol0 & 1023;
    const int h = col_in >> 6;
    if (sel < 2) {
#pragma unroll
      for (int i = 0; i < 8; ++i)
#pragma unroll
        for (int r = 0; r < 4; ++r) {
          float s = 0.f;
#pragma unroll
          for (int j = 0; j < 4; ++j) s += acc[i][j][r] * acc[i][j][r];
          s += __shfl_xor(s, 1); s += __shfl_xor(s, 2);
          s += __shfl_xor(s, 4); s += __shfl_xor(s, 8);
          const float inv = 1.f / fmaxf(sqrtf(s), 1e-12f);
#pragma unroll
          for (int j = 0; j < 4; ++j) acc[i][j][r] *= inv;
        }
    } else {
      const float sig = 1.f / (1.f + expf(-nc[h]));
      const float vsc = expf(-6.9314718055994530942f * sig);  // 1024^-sig
#pragma unroll
      for (int i = 0; i < 8; ++i)
#pragma unroll
        for (int j = 0; j < 4; ++j)
#pragma unroll
          for (int r = 0; r < 4; ++r) acc[i][j][r] *= vsc;
    }
    if (sel == 0) {
      unsigned short* Op = (unsigned short*)O0;
      const int colb = col_in + (l & 15);
#pragma unroll
      for (int i = 0; i < 8; ++i)
#pragma unroll
        for (int j = 0; j < 4; ++j)
#pragma unroll
          for (int r = 0; r < 4; ++r)
            Op[(long long)(rowb + i * 16 + r) * 1024 + (colb + j * 16)] = f2bf(acc[i][j][r]);
    } else {
      // transposed: T[(n*16+h)*64 + d][c],  d = j*16+(l&15), c = c0 + i*16 + r
      unsigned short* Tp = (unsigned short*)(sel == 1 ? O1 : O2)
                         + ((long long)((bm0 >> 10) * 16 + h) * 64) * 1024;
      const int c0 = (bm0 & 1023) + wm * 128 + (l >> 4) * 4;
#pragma unroll
      for (int i = 0; i < 8; ++i)
#pragma unroll
        for (int j = 0; j < 4; ++j)
#pragma unroll
          for (int r = 0; r < 4; ++r)
            Tp[(long long)(j * 16 + (l & 15)) * 1024 + (c0 + i * 16 + r)] = f2bf(acc[i][j][r]);
    }
  }
}

// ---------------- kvT[e][d] = sum_c vT[e][c]*kT[d][c] per (n,h), MFMA split-K ----------------
// 4 waves, each K-range 256; wave-private dbuf gload_lds staging; LDS reduce at end.
__global__ __launch_bounds__(256) void kv_mfma(
    const unsigned short* __restrict__ vT, const unsigned short* __restrict__ kT,
    unsigned short* __restrict__ kvT)
{
  const int h = blockIdx.x, n = blockIdx.y;
  const int t = threadIdx.x, l = t & 63, w = t >> 6;
  __shared__ char smem[131072];
  const long long base = (long long)(n * 16 + h) * 64 * 1024;
  const int srow = l >> 3;
  const int schunk = l & 7;
  char* wbuf = smem + w * 32768;

#define KV_STAGE(buf_, cc_) do {                                                                  \
    const int col_ = w * 256 + (cc_) * 64;                                                        \
    _Pragma("unroll")                                                                             \
    for (int i_ = 0; i_ < 8; ++i_) {                                                              \
      const int r_ = i_ * 8 + srow;                                                               \
      const int sc_ = schunk ^ srow;                                                              \
      __builtin_amdgcn_global_load_lds((gmem_t*)(vT + base + (long long)r_ * 1024 + col_ + sc_ * 8), \
                                       (lds_t*)((buf_) + r_ * 128 + schunk * 16), 16, 0, 0);      \
      __builtin_amdgcn_global_load_lds((gmem_t*)(kT + base + (long long)r_ * 1024 + col_ + sc_ * 8), \
                                       (lds_t*)((buf_) + 8192 + r_ * 128 + schunk * 16), 16, 0, 0); \
    }                                                                                             \
  } while (0)

  const int xr = l & 7, chalf = l >> 4;
  f32x4 acc[4][4];
#pragma unroll
  for (int i = 0; i < 4; ++i)
#pragma unroll
    for (int j = 0; j < 4; ++j) acc[i][j] = f32x4{0.f, 0.f, 0.f, 0.f};

  KV_STAGE(wbuf, 0);
  for (int cc = 0; cc < 4; ++cc) {
    char* cur = wbuf + (cc & 1) * 16384;
    if (cc < 3) {
      KV_STAGE(wbuf + ((cc + 1) & 1) * 16384, cc + 1);
      asm volatile("s_waitcnt vmcnt(16)" ::: "memory");
    } else {
      asm volatile("s_waitcnt vmcnt(0)" ::: "memory");
    }
    bf16x8 av[4][2], bvv[4][2];
#pragma unroll
    for (int m = 0; m < 4; ++m)
#pragma unroll
      for (int ks = 0; ks < 2; ++ks) {
        const int ch = ((ks * 4 + chalf) ^ xr) * 16;
        av[m][ks]  = *(const bf16x8*)(cur + (m * 16 + (l & 15)) * 128 + ch);
        bvv[m][ks] = *(const bf16x8*)(cur + 8192 + (m * 16 + (l & 15)) * 128 + ch);
      }
#pragma unroll
    for (int m = 0; m < 4; ++m)
#pragma unroll
      for (int j = 0; j < 4; ++j)
#pragma unroll
        for (int ks = 0; ks < 2; ++ks)
          acc[m][j] = __builtin_amdgcn_mfma_f32_16x16x32_bf16(av[m][ks], bvv[j][ks], acc[m][j], 0, 0, 0);
  }
#undef KV_STAGE

  __syncthreads();
  float* red = (float*)smem;                        // [4 waves][16 frags][256]
#pragma unroll
  for (int m = 0; m < 4; ++m)
#pragma unroll
    for (int j = 0; j < 4; ++j)
      *(f32x4*)&red[w * 4096 + (m * 4 + j) * 256 + l * 4] = acc[m][j];
  __syncthreads();

  // gather: thread t -> e = t>>2, d-range (t&3)*16..+15
  const int e = t >> 2, d0 = (t & 3) * 16;
  const int m = e >> 4, rr = e & 3, lhi = (e & 15) >> 2;
  alignas(16) unsigned short o16[16];
#pragma unroll
  for (int dd = 0; dd < 16; ++dd) {
    const int d = d0 + dd;
    const int f = m * 4 + (d >> 4);
    const int pos = (lhi * 16 + (d & 15)) * 4 + rr;
    float s = red[f * 256 + pos] + red[4096 + f * 256 + pos] +
              red[8192 + f * 256 + pos] + red[12288 + f * 256 + pos];
    o16[dd] = f2bf(s);
  }
  unsigned short* dst = kvT + (long long)(n * 16 + h) * 4096 + e * 64 + d0;
  *(u32x4*)dst = *(const u32x4*)&o16[0];
  *((u32x4*)dst + 1) = *(const u32x4*)&o16[8];
}

// ---------------- attn[c][h*64+e] = sum_d q[c][h*64+d]*kvT[e][d]; in-place over q ----------------
__global__ __launch_bounds__(256) void attn_mfma(
    unsigned short* __restrict__ q, const unsigned short* __restrict__ kvT)
{
  const int ct = blockIdx.x, h = blockIdx.y, n = blockIdx.z;
  const int t = threadIdx.x, l = t & 63, w = t >> 6;
  __shared__ char smem[40960];                     // q tile 32KB + kvT 8KB
  const long long R0 = (long long)n * 1024 + ct * 256;
  {
    const int sr = t >> 3;                         // 0..31
    const int sc = (t & 7) ^ (sr & 7);
#pragma unroll
    for (int i = 0; i < 8; ++i) {
      const int r = i * 32 + sr;
      __builtin_amdgcn_global_load_lds((gmem_t*)(q + (R0 + r) * 1024 + h * 64 + sc * 8),
                                       (lds_t*)(smem + r * 128 + (t & 7) * 16), 16, 0, 0);
    }
#pragma unroll
    for (int i = 0; i < 2; ++i) {
      const int r = i * 32 + sr;
      __builtin_amdgcn_global_load_lds((gmem_t*)(kvT + (long long)(n * 16 + h) * 4096 + r * 64 + sc * 8),
                                       (lds_t*)(smem + 32768 + r * 128 + (t & 7) * 16), 16, 0, 0);
    }
  }
  asm volatile("s_waitcnt vmcnt(0)" ::: "memory");
  __syncthreads();

  const int xr = l & 7, chalf = l >> 4;
  f32x4 acc[4][4];
#pragma unroll
  for (int i = 0; i < 4; ++i)
#pragma unroll
    for (int j = 0; j < 4; ++j) acc[i][j] = f32x4{0.f, 0.f, 0.f, 0.f};
  bf16x8 av[4][2], bvv[4][2];
#pragma unroll
  for (int m = 0; m < 4; ++m)
#pragma unroll
    for (int ks = 0; ks < 2; ++ks) {
      const int ch = ((ks * 4 + chalf) ^ xr) * 16;
      av[m][ks]  = *(const bf16x8*)(smem + (w * 64 + m * 16 + (l & 15)) * 128 + ch);
      bvv[m][ks] = *(const bf16x8*)(smem + 32768 + (m * 16 + (l & 15)) * 128 + ch);
    }
#pragma unroll
  for (int m = 0; m < 4; ++m)
#pragma unroll
    for (int j = 0; j < 4; ++j)
#pragma unroll
      for (int ks = 0; ks < 2; ++ks)
        acc[m][j] = __builtin_amdgcn_mfma_f32_16x16x32_bf16(av[m][ks], bvv[j][ks], acc[m][j], 0, 0, 0);

  // write in place: row = R0 + w*64 + m*16 + (l>>4)*4 + r, col = h*64 + j*16 + (l&15)
  const int rb = w * 64 + (l >> 4) * 4;
#pragma unroll
  for (int m = 0; m < 4; ++m)
#pragma unroll
    for (int j = 0; j < 4; ++j)
#pragma unroll
      for (int r = 0; r < 4; ++r)
        q[(R0 + rb + m * 16 + r) * 1024 + h * 64 + j * 16 + (l & 15)] = f2bf(acc[m][j][r]);
}

extern "C" void kernel_launch(void* const* d_in, const int* in_sizes, int n_in,
                              void* d_out, int out_size, void* d_ws, size_t ws_size,
                              hipStream_t stream) {
  (void)in_sizes; (void)n_in; (void)out_size; (void)ws_size;
  const float* x  = (const float*)d_in[0];
  const float* Wq = (const float*)d_in[1];
  const float* Wk = (const float*)d_in[2];
  const float* Wv = (const float*)d_in[3];
  const float* Wo = (const float*)d_in[4];
  const float* nc = (const float*)d_in[5];

  // d_out (64 MB fp32) scratch: xb [0,32MB) (dead after QKV), kvT at +32MB (dead before Wo write)
  unsigned short* xb  = (unsigned short*)d_out;
  unsigned short* kvT = (unsigned short*)((char*)d_out + 33554432ll);

  char* ws = (char*)d_ws;
  unsigned short* wqkv = (unsigned short*)ws;          // [3072][1024] = Wq;Wk;Wv
  unsigned short* wob  = wqkv + 3 * 1048576;
  unsigned short* qb   = wob + 1048576;                // q, then attn in place
  unsigned short* kTb  = qb + 16777216;                // k transposed [n][h][64][1024]
  unsigned short* vTb  = kTb + 16777216;               // v transposed [n][h][64][1024]

  cvt_kernel<<<8192, 256, 0, stream>>>(x, xb, 16777216);
  cvtw_kernel<<<dim3(512, 4), 256, 0, stream>>>(Wq, Wk, Wv, Wo, wqkv, wob);

  gemm256<12, 1><<<dim3(12, 64), 512, 0, stream>>>(xb, wqkv, qb, kTb, vTb, nc);
  kv_mfma<<<dim3(16, 16), 256, 0, stream>>>(vTb, kTb, kvT);
  attn_mfma<<<dim3(4, 16, 16), 256, 0, stream>>>(qb, kvT);
  gemm256<4, 0><<<dim3(4, 64), 512, 0, stream>>>(qb, wob, d_out, nullptr, nullptr, nullptr);
}